// Round 11
// baseline (670.772 us; speedup 1.0000x reference)
//
#include <hip/hip_runtime.h>

typedef unsigned short u16;
typedef unsigned int u32;
typedef long long ll;
typedef __attribute__((ext_vector_type(8))) short bf16x8;
typedef __attribute__((ext_vector_type(8))) unsigned short u16x8;
typedef __attribute__((ext_vector_type(4))) float f32x4;

__device__ __forceinline__ u16 f2bf(float f) {
  u32 x = __float_as_uint(f);
  x += 0x7fffu + ((x >> 16) & 1u);
  return (u16)(x >> 16);
}
__device__ __forceinline__ float bf2f(u16 u) {
  return __uint_as_float(((u32)u) << 16);
}

__device__ __forceinline__ int read_pad(const int* pw, int z) {
  int odd = pw[1] | pw[3] | pw[5] | pw[7] | pw[9] | pw[11] | pw[13] | pw[15];
  return (odd == 0) ? pw[2 * z] : pw[z];
}

// ===========================================================================
// Fragment-tiled layout: operand [rows][K] stored as frags (rb = row>>4,
// ks = k>>5); frag = 1 KB: lane l holds 8 bf16 at row rb*16+(l&15),
// k = ks*32+(l>>4)*8.  u16 offset = (rb*KS + ks)*512 + l*8.
// Both A (rows=M) and B (rows=N) use the identical layout.
// ===========================================================================

// ===========================================================================
// gfrag: NO-LDS register GEMM (AITER-style MFMA<->load interleave).
// C = A*B^T, 128x128 block, 4 waves (2x2), 64x64/wave, acc 64 VGPR.
// 2-deep register prefetch (a0/b0 and a1/b1 named sets, all static idx).
// No barriers, no LDS -> 3 blocks/CU; cross-wave overlap hides L2 latency.
// EPI: 0 = scale+mask+exp -> frag-tiled bf16 P' + rowsum atomics
//      2 = fp32 + bias row-major;  3 = frag-tiled bf16 * (1/lsum[row]).
// ===========================================================================
template<int EPI>
__global__ __launch_bounds__(256, 3) void gfrag(
    const u16* __restrict__ A, const u16* __restrict__ B, void* __restrict__ C,
    int KS, int KSo, int ldc, ll sA, ll sB, ll sC,
    const int* __restrict__ pad, const float* __restrict__ bias,
    float* __restrict__ lsum, int NX, int NXY, int nwg) {
  // bijective XCD swizzle (m204) + decode
  const int orig = blockIdx.x;
  const int q8 = nwg >> 3, r8 = nwg & 7;
  const int xcd = orig & 7, inner = orig >> 3;
  const int wg = (xcd < r8 ? xcd * (q8 + 1) : r8 * (q8 + 1) + (xcd - r8) * q8) + inner;
  const int z = wg / NXY;
  const int rem = wg - z * NXY;
  const int by = rem / NX;
  const int bx = rem - by * NX;

  const int tid = threadIdx.x;
  const int wid = tid >> 6, lane = tid & 63;
  const int lr = lane & 15, lg = lane >> 4;
  const int mb0 = by * 8 + (wid >> 1) * 4;  // wave's first m-frag (16 rows each)
  const int nb0 = bx * 8 + (wid & 1) * 4;   // wave's first n-frag
  const u16* Ap = A + (ll)z * sA + (ll)mb0 * KS * 512 + lane * 8;
  const u16* Bp = B + (ll)z * sB + (ll)nb0 * KS * 512 + lane * 8;

  f32x4 acc[4][4];
#pragma unroll
  for (int i = 0; i < 4; ++i)
#pragma unroll
    for (int j = 0; j < 4; ++j) acc[i][j] = (f32x4)0.0f;

  bf16x8 a0[4], b0[4], a1[4], b1[4];
#pragma unroll
  for (int i = 0; i < 4; ++i) {
    a0[i] = *(const bf16x8*)(Ap + (ll)i * KS * 512);
    b0[i] = *(const bf16x8*)(Bp + (ll)i * KS * 512);
  }
#pragma unroll
  for (int i = 0; i < 4; ++i) {
    a1[i] = *(const bf16x8*)(Ap + ((ll)i * KS + 1) * 512);
    b1[i] = *(const bf16x8*)(Bp + ((ll)i * KS + 1) * 512);
  }
  for (int ks = 0; ks < KS - 2; ks += 2) {
#pragma unroll
    for (int i = 0; i < 4; ++i)
#pragma unroll
      for (int j = 0; j < 4; ++j)
        acc[i][j] = __builtin_amdgcn_mfma_f32_16x16x32_bf16(a0[i], b0[j],
                                                            acc[i][j], 0, 0, 0);
#pragma unroll
    for (int i = 0; i < 4; ++i) {
      a0[i] = *(const bf16x8*)(Ap + ((ll)i * KS + ks + 2) * 512);
      b0[i] = *(const bf16x8*)(Bp + ((ll)i * KS + ks + 2) * 512);
    }
#pragma unroll
    for (int i = 0; i < 4; ++i)
#pragma unroll
      for (int j = 0; j < 4; ++j)
        acc[i][j] = __builtin_amdgcn_mfma_f32_16x16x32_bf16(a1[i], b1[j],
                                                            acc[i][j], 0, 0, 0);
#pragma unroll
    for (int i = 0; i < 4; ++i) {
      a1[i] = *(const bf16x8*)(Ap + ((ll)i * KS + ks + 3) * 512);
      b1[i] = *(const bf16x8*)(Bp + ((ll)i * KS + ks + 3) * 512);
    }
  }
#pragma unroll
  for (int i = 0; i < 4; ++i)
#pragma unroll
    for (int j = 0; j < 4; ++j)
      acc[i][j] = __builtin_amdgcn_mfma_f32_16x16x32_bf16(a0[i], b0[j],
                                                          acc[i][j], 0, 0, 0);
#pragma unroll
  for (int i = 0; i < 4; ++i)
#pragma unroll
    for (int j = 0; j < 4; ++j)
      acc[i][j] = __builtin_amdgcn_mfma_f32_16x16x32_bf16(a1[i], b1[j],
                                                          acc[i][j], 0, 0, 0);

  // ---- epilogue: C/D layout col = lane&15, row = (lane>>4)*4 + reg --------
  int p = 0;
  if constexpr (EPI == 0) p = read_pad(pad, z);
#pragma unroll
  for (int mf = 0; mf < 4; ++mf) {
#pragma unroll
    for (int rg = 0; rg < 4; ++rg) {
      const int row = (mb0 + mf) * 16 + 4 * lg + rg;
      if constexpr (EPI == 0) {
        float part = 0.0f;
#pragma unroll
        for (int nf = 0; nf < 4; ++nf) {
          const int col = (nb0 + nf) * 16 + lr;
          float e;
          if (row >= p && col >= p) e = (p == 0) ? 1.0f : 0.0f;
          else e = __expf(acc[mf][nf][rg] * 0.03125f);
          part += e;
          ((u16*)C)[(ll)z * sC + ((ll)(row >> 4) * KSo + (col >> 5)) * 512 +
                    (((row & 15) | (((col >> 3) & 3) << 4)) << 3) + (col & 7)] =
              f2bf(e);
        }
        part += __shfl_xor(part, 1);
        part += __shfl_xor(part, 2);
        part += __shfl_xor(part, 4);
        part += __shfl_xor(part, 8);
        if (lr == 0) atomicAdd(&lsum[z * 2048 + row], part);
      } else if constexpr (EPI == 3) {
        const float linv = 1.0f / lsum[z * 2048 + row];
#pragma unroll
        for (int nf = 0; nf < 4; ++nf) {
          const int col = (nb0 + nf) * 16 + lr;
          ((u16*)C)[(ll)z * sC + ((ll)(row >> 4) * KSo + (col >> 5)) * 512 +
                    (((row & 15) | (((col >> 3) & 3) << 4)) << 3) + (col & 7)] =
              f2bf(acc[mf][nf][rg] * linv);
        }
      } else {
#pragma unroll
        for (int nf = 0; nf < 4; ++nf) {
          const int col = (nb0 + nf) * 16 + lr;
          ((float*)C)[(ll)row * ldc + col] = acc[mf][nf][rg] + bias[col];
        }
      }
    }
  }
}

// ===========================================================================
// Prologue kernels (Tier A)
// ===========================================================================
__global__ __launch_bounds__(256) void zerof(float* __restrict__ p) {
  p[blockIdx.x * 256 + threadIdx.x] = 0.0f;
}

// fp32 [R][1024] row-major -> frag-tiled bf16 (KS = 32).  One 16-row stripe
// per block.  LDS [16][1032] u16 (pad kills the 16-way bank conflict).
__global__ __launch_bounds__(256) void cvtA_frag(const float* __restrict__ src,
                                                 u16* __restrict__ dst) {
  __shared__ u16 t[16 * 1032];
  const int tid = threadIdx.x;
  const ll rb = (ll)blockIdx.x * 16;
#pragma unroll
  for (int it = 0; it < 8; ++it) {
    const int ch = it * 256 + tid;  // 2048 chunks of 8 elems
    const int r = ch >> 7, kc = (ch & 127) * 8;
    const float4 a = *(const float4*)(src + (rb + r) * 1024 + kc);
    const float4 b = *(const float4*)(src + (rb + r) * 1024 + kc + 4);
    u16x8 v;
    v[0] = f2bf(a.x); v[1] = f2bf(a.y); v[2] = f2bf(a.z); v[3] = f2bf(a.w);
    v[4] = f2bf(b.x); v[5] = f2bf(b.y); v[6] = f2bf(b.z); v[7] = f2bf(b.w);
    *(u16x8*)(t + r * 1032 + kc) = v;
  }
  __syncthreads();
#pragma unroll
  for (int it = 0; it < 8; ++it) {
    const int fl = it * 256 + tid;  // 32 frags x 64 lanes
    const int ks = fl >> 6, l = fl & 63;
    const u16x8 v = *(const u16x8*)(t + (l & 15) * 1032 + ks * 32 + (l >> 4) * 8);
    *(u16x8*)(dst + ((ll)blockIdx.x * 32 + ks) * 512 + l * 8) = v;
  }
}

// fp32 [R][C] -> transpose -> frag-tiled bf16 of [C][R] (KSo = R/32).
__global__ __launch_bounds__(256) void transpose_frag(
    const float* __restrict__ src, u16* __restrict__ dst, int R, int C,
    ll sS, ll sD) {
  __shared__ u16 t[64][65];
  const int tid = threadIdx.x;
  const int r0 = blockIdx.y * 64, c0 = blockIdx.x * 64;
  const float* s = src + (ll)blockIdx.z * sS;
  u16* d = dst + (ll)blockIdx.z * sD;
#pragma unroll
  for (int it = 0; it < 16; ++it) {
    const int idx = it * 256 + tid;
    const int r = idx >> 6, c = idx & 63;
    t[r][c] = f2bf(s[(ll)(r0 + r) * C + c0 + c]);
  }
  __syncthreads();
  const int KSo = R >> 5;
#pragma unroll
  for (int it = 0; it < 2; ++it) {
    const int fl = it * 256 + tid;  // 8 frags x 64 lanes
    const int f = fl >> 6, l = fl & 63;
    const int db = f >> 1, ss = f & 1;
    u16x8 v;
#pragma unroll
    for (int e = 0; e < 8; ++e)
      v[e] = t[ss * 32 + (l >> 4) * 8 + e][db * 16 + (l & 15)];
    *(u16x8*)(d + ((ll)((c0 >> 4) + db) * KSo + ((r0 >> 5) + ss)) * 512 + l * 8) = v;
  }
}

// ===========================================================================
// Fallback-tier kernels (Tier B/C): plain-layout pipeline from R10.
// ===========================================================================
__global__ __launch_bounds__(256) void transpose_cvt(
    const float* __restrict__ src, u16* __restrict__ dst, int R, int C,
    ll sS, ll sD) {
  __shared__ u16 t[64][65];
  const int tid = threadIdx.x;
  const int r0 = blockIdx.y * 64, c0 = blockIdx.x * 64;
  const float* s = src + (ll)blockIdx.z * sS;
  u16* d = dst + (ll)blockIdx.z * sD;
#pragma unroll
  for (int it = 0; it < 16; ++it) {
    const int idx = it * 256 + tid;
    const int r = idx >> 6, c = idx & 63;
    t[r][c] = f2bf(s[(ll)(r0 + r) * C + c0 + c]);
  }
  __syncthreads();
#pragma unroll
  for (int it = 0; it < 16; ++it) {
    const int idx = it * 256 + tid;
    const int rr = idx >> 6, cc = idx & 63;
    d[(ll)(c0 + rr) * R + r0 + cc] = t[cc][rr];
  }
}

template<int EPI>  // 1 = bf16 store; 2 = fp32 + bias
__global__ __launch_bounds__(256, 4) void g128(
    const u16* __restrict__ A, const u16* __restrict__ B, void* __restrict__ C,
    int Kdim, int lda, int ldb, int ldc, ll sA, ll sB, ll sC,
    const float* __restrict__ bias, int NX, int NXY, int nwg) {
  __shared__ __align__(16) u16 As[128 * 64];
  __shared__ __align__(16) u16 Bs[128 * 64];
  const int orig = blockIdx.x;
  const int q8 = nwg >> 3, r8 = nwg & 7;
  const int xcd = orig & 7, inner = orig >> 3;
  const int wg = (xcd < r8 ? xcd * (q8 + 1) : r8 * (q8 + 1) + (xcd - r8) * q8) + inner;
  const int z = wg / NXY;
  const int rem = wg - z * NXY;
  const int by = rem / NX;
  const int bx = rem - by * NX;
  const int tid = threadIdx.x;
  const int wid = tid >> 6, lane = tid & 63;
  const int lr = lane & 15, lg = lane >> 4;
  const int wm = (wid >> 1) * 64, wn = (wid & 1) * 64;
  const int bm = by * 128, bn = bx * 128;
  const u16* Ab = A + (ll)z * sA + (ll)bm * lda;
  const u16* Bb = B + (ll)z * sB + (ll)bn * ldb;

  f32x4 acc[4][4];
#pragma unroll
  for (int i = 0; i < 4; ++i)
#pragma unroll
    for (int j = 0; j < 4; ++j) acc[i][j] = (f32x4)0.0f;

  const int NT = Kdim >> 6;
  for (int t = 0; t < NT; ++t) {
    __syncthreads();
#pragma unroll
    for (int i = 0; i < 4; ++i) {
      const int chunk = i * 256 + tid;
      const int r = chunk >> 3;
      const int slot = chunk & 7;
      const int gk = t * 64 + ((slot ^ (r & 7)) * 8);
      __builtin_amdgcn_global_load_lds(
          (const __attribute__((address_space(1))) void*)(Ab + (ll)r * lda + gk),
          (__attribute__((address_space(3))) void*)(As + chunk * 8), 16, 0, 0);
      __builtin_amdgcn_global_load_lds(
          (const __attribute__((address_space(1))) void*)(Bb + (ll)r * ldb + gk),
          (__attribute__((address_space(3))) void*)(Bs + chunk * 8), 16, 0, 0);
    }
    __syncthreads();
#pragma unroll
    for (int kk = 0; kk < 2; ++kk) {
      bf16x8 av[4], bv[4];
#pragma unroll
      for (int i = 0; i < 4; ++i) {
        const int ra = wm + i * 16 + lr;
        av[i] = *(const bf16x8*)(As + ra * 64 + (((kk * 4 + lg) ^ (ra & 7)) * 8));
        const int rb = wn + i * 16 + lr;
        bv[i] = *(const bf16x8*)(Bs + rb * 64 + (((kk * 4 + lg) ^ (rb & 7)) * 8));
      }
#pragma unroll
      for (int i = 0; i < 4; ++i)
#pragma unroll
        for (int j = 0; j < 4; ++j)
          acc[i][j] = __builtin_amdgcn_mfma_f32_16x16x32_bf16(av[i], bv[j],
                                                              acc[i][j], 0, 0, 0);
    }
  }
#pragma unroll
  for (int mf = 0; mf < 4; ++mf) {
#pragma unroll
    for (int rg = 0; rg < 4; ++rg) {
      const int row = bm + wm + mf * 16 + 4 * lg + rg;
#pragma unroll
      for (int nf = 0; nf < 4; ++nf) {
        const int col = bn + wn + nf * 16 + lr;
        if constexpr (EPI == 1) {
          ((u16*)C)[(ll)z * sC + (ll)row * ldc + col] = f2bf(acc[mf][nf][rg]);
        } else {
          ((float*)C)[(ll)z * sC + (ll)row * ldc + col] =
              acc[mf][nf][rg] + bias[col];
        }
      }
    }
  }
}

__global__ __launch_bounds__(256) void softmax_rows(u16* __restrict__ P,
                                                    const int* __restrict__ pad) {
  const int wid = threadIdx.x >> 6, lane = threadIdx.x & 63;
  const ll row = (ll)blockIdx.x * 4 + wid;
  const int z = (int)(row >> 11);
  const int r = (int)(row & 2047);
  const int p = read_pad(pad, z);
  const bool rmask = (r >= p);
  u16* ptr = P + row * 2048;
  float s[32];
#pragma unroll
  for (int i = 0; i < 4; ++i) {
    const u16x8 v = *(const u16x8*)(ptr + i * 512 + lane * 8);
#pragma unroll
    for (int j = 0; j < 8; ++j) {
      const int col = i * 512 + lane * 8 + j;
      float x = bf2f(v[j]) * 0.03125f;
      if (rmask && col >= p) x = -1e13f;
      s[i * 8 + j] = x;
    }
  }
  float m = s[0];
#pragma unroll
  for (int i = 1; i < 32; ++i) m = fmaxf(m, s[i]);
#pragma unroll
  for (int o = 1; o < 64; o <<= 1) m = fmaxf(m, __shfl_xor(m, o));
  float sum = 0.0f;
#pragma unroll
  for (int i = 0; i < 32; ++i) {
    s[i] = __expf(s[i] - m);
    sum += s[i];
  }
#pragma unroll
  for (int o = 1; o < 64; o <<= 1) sum += __shfl_xor(sum, o);
  const float inv = 1.0f / sum;
#pragma unroll
  for (int i = 0; i < 4; ++i) {
    u16x8 v;
#pragma unroll
    for (int j = 0; j < 8; ++j) v[j] = f2bf(s[i * 8 + j] * inv);
    *(u16x8*)(ptr + i * 512 + lane * 8) = v;
  }
}

__device__ __forceinline__ void stage_f32(const float* src, ll base, int ld,
                                          u16* lds, int tid) {
#pragma unroll
  for (int p = 0; p < 4; ++p) {
    int chunk = p * 256 + tid;
    int r = chunk >> 3, slot = chunk & 7;
    const float* s = src + base + (ll)r * ld + slot * 8;
    const float4 a = *(const float4*)s;
    const float4 b = *(const float4*)(s + 4);
    u16x8 v;
    v[0] = f2bf(a.x); v[1] = f2bf(a.y); v[2] = f2bf(a.z); v[3] = f2bf(a.w);
    v[4] = f2bf(b.x); v[5] = f2bf(b.y); v[6] = f2bf(b.z); v[7] = f2bf(b.w);
    *(u16x8*)(lds + r * 64 + (slot ^ (r & 7)) * 8) = v;
  }
}

__global__ __launch_bounds__(256) void gemm_f32in(
    const float* __restrict__ A, const float* __restrict__ B,
    u16* __restrict__ C, int Kdim, int lda, int ldb, int ldc,
    ll sA, ll sB, ll sC) {
  __shared__ __align__(16) u16 As[128 * 64];
  __shared__ __align__(16) u16 Bs[128 * 64];
  const int tid = threadIdx.x;
  const int z = blockIdx.z;
  const int bm = blockIdx.y * 128, bn = blockIdx.x * 128;
  const ll abase = (ll)z * sA + (ll)bm * lda;
  const ll bbase = (ll)z * sB + (ll)bn * ldb;
  const int wid = tid >> 6, lane = tid & 63;
  const int wm = (wid >> 1) * 64, wn = (wid & 1) * 64;
  const int lr = lane & 15, lg = lane >> 4;

  f32x4 acc[4][4];
#pragma unroll
  for (int i = 0; i < 4; ++i)
#pragma unroll
    for (int j = 0; j < 4; ++j) acc[i][j] = (f32x4)0.0f;

  for (int k0 = 0; k0 < Kdim; k0 += 64) {
    __syncthreads();
    stage_f32(A, abase + k0, lda, As, tid);
    stage_f32(B, bbase + k0, ldb, Bs, tid);
    __syncthreads();
#pragma unroll
    for (int kk = 0; kk < 2; ++kk) {
      bf16x8 av[4], bv[4];
#pragma unroll
      for (int i = 0; i < 4; ++i) {
        const int ra = wm + i * 16 + lr;
        av[i] = *(const bf16x8*)(As + ra * 64 + (((kk * 4 + lg) ^ (ra & 7)) * 8));
        const int rb = wn + i * 16 + lr;
        bv[i] = *(const bf16x8*)(Bs + rb * 64 + (((kk * 4 + lg) ^ (rb & 7)) * 8));
      }
#pragma unroll
      for (int i = 0; i < 4; ++i)
#pragma unroll
        for (int j = 0; j < 4; ++j)
          acc[i][j] = __builtin_amdgcn_mfma_f32_16x16x32_bf16(av[i], bv[j],
                                                              acc[i][j], 0, 0, 0);
    }
  }
#pragma unroll
  for (int i = 0; i < 4; ++i) {
    const int rowb = bm + wm + i * 16 + 4 * lg;
#pragma unroll
    for (int j = 0; j < 4; ++j) {
      const int col = bn + wn + j * 16 + lr;
#pragma unroll
      for (int rg = 0; rg < 4; ++rg)
        C[(ll)z * sC + (ll)(rowb + rg) * ldc + col] = f2bf(acc[i][j][rg]);
    }
  }
}

// ===========================================================================
extern "C" void kernel_launch(void* const* d_in, const int* in_sizes, int n_in,
                              void* d_out, int out_size, void* d_ws,
                              size_t ws_size, hipStream_t stream) {
  const float* Q = (const float*)d_in[0];
  const float* Km = (const float*)d_in[1];
  const float* V = (const float*)d_in[2];
  const int* pad = (const int*)d_in[3];
  const float* W = (const float*)d_in[4];
  const float* bias = (const float*)d_in[5];
  float* out = (float*)d_out;

  const int B = 16, S = 2048, D = 1024, E = 1024;
  const ll SS = (ll)S * S, SD = (ll)S * D;

  u16* P = (u16*)d_out;   // 128 MB bf16 exp-scores (frag-tiled); overwritten
  char* ws = (char*)d_ws;

  const size_t MB64 = (size_t)B * S * D * 2;  // 64 MB
  const size_t szWt = (size_t)D * E * 2;      // 2 MB
  const size_t szL = (size_t)B * S * 4;       // 128 KB row-sums

  if (ws_size >= 3 * MB64 + szWt + szL) {
    // Tier A: no-LDS fragment-direct GEMMs + fused softmax.
    u16* Qb = (u16*)ws;                      // frag-tiled A (QK)
    u16* Kb = (u16*)(ws + MB64);             // frag-tiled B (QK)
    u16* Vt = (u16*)(ws + 2 * MB64);         // frag-tiled B (PV), KSo=64
    u16* Wt = (u16*)(ws + 3 * MB64);         // frag-tiled B (out), KSo=32
    float* lsum = (float*)(ws + 3 * MB64 + szWt);
    u16* X = Qb;  // frag-tiled A (out); aliases Qb (dead after QK)

    zerof<<<dim3(B * S / 256), 256, 0, stream>>>(lsum);
    cvtA_frag<<<dim3(B * S / 16), 256, 0, stream>>>(Q, Qb);
    cvtA_frag<<<dim3(B * S / 16), 256, 0, stream>>>(Km, Kb);
    transpose_frag<<<dim3(D / 64, S / 64, B), 256, 0, stream>>>(V, Vt, S, D, SD, SD);
    transpose_frag<<<dim3(E / 64, D / 64, 1), 256, 0, stream>>>(W, Wt, D, E, 0, 0);

    // QK + exp/mask + rowsum: 16x16 blocks x 16 batches (KS=32, KSo=64)
    gfrag<0><<<dim3(4096), 256, 0, stream>>>(
        Qb, Kb, P, 32, 64, 0, SD, SD, SS, pad, nullptr, lsum, 16, 256, 4096);
    // PV + normalize: 16x8 blocks x 16 batches (KS=64, KSo=32)
    gfrag<3><<<dim3(2048), 256, 0, stream>>>(
        P, Vt, X, 64, 32, 0, SS, SD, SD, nullptr, nullptr, lsum, 8, 128, 2048);
    // out-proj: 256x8 blocks (KS=32, row-major fp32 out)
    gfrag<2><<<dim3(2048), 256, 0, stream>>>(
        X, Wt, out, 32, 0, E, 0, 0, 0, nullptr, bias, nullptr, 8, 2048, 2048);
  } else if (ws_size >= 2 * MB64 + szWt) {
    // Tier B: plain-layout pipeline (R10 kernels).
    u16* Vt = (u16*)ws;
    u16* Wt = (u16*)(ws + MB64);
    u16* X = (u16*)(ws + MB64 + szWt);

    transpose_cvt<<<dim3(D / 64, S / 64, B), 256, 0, stream>>>(V, Vt, S, D, SD, SD);
    transpose_cvt<<<dim3(E / 64, D / 64, 1), 256, 0, stream>>>(W, Wt, D, E, 0, 0);
    gemm_f32in<<<dim3(S / 128, S / 128, B), 256, 0, stream>>>(
        Q, Km, (u16*)d_out, D, D, D, S, SD, SD, SS);
    softmax_rows<<<dim3(B * S / 4), 256, 0, stream>>>((u16*)d_out, pad);
    g128<1><<<dim3(2048), 256, 0, stream>>>(
        (u16*)d_out, Vt, X, S, S, S, D, SS, SD, SD, nullptr, 8, 128, 2048);
    g128<2><<<dim3(2048), 256, 0, stream>>>(
        X, Wt, out, D, D, D, E, 0, 0, 0, bias, 8, 2048, 2048);
  } else {
    // Tier C: per-batch V transpose (needs >= 70 MB).
    u16* Wt = (u16*)ws;
    u16* Vtb = (u16*)(ws + szWt);
    u16* X = (u16*)(ws + szWt + (size_t)D * S * 2);

    transpose_cvt<<<dim3(E / 64, D / 64, 1), 256, 0, stream>>>(W, Wt, D, E, 0, 0);
    gemm_f32in<<<dim3(S / 128, S / 128, B), 256, 0, stream>>>(
        Q, Km, (u16*)d_out, D, D, D, S, SD, SD, SS);
    softmax_rows<<<dim3(B * S / 4), 256, 0, stream>>>((u16*)d_out, pad);
    for (int b = 0; b < B; ++b) {
      transpose_cvt<<<dim3(D / 64, S / 64, 1), 256, 0, stream>>>(
          V + (ll)b * SD, Vtb, S, D, 0, 0);
      g128<1><<<dim3(128), 256, 0, stream>>>(
          (u16*)d_out + (ll)b * SS, Vtb, X + (ll)b * SD, S, S, S, D, 0, 0, 0,
          nullptr, 8, 128, 128);
    }
    g128<2><<<dim3(2048), 256, 0, stream>>>(
        X, Wt, out, D, D, D, E, 0, 0, 0, bias, 8, 2048, 2048);
  }
}

// Round 12
// 524.991 us; speedup vs baseline: 1.2777x; 1.2777x over previous
//
#include <hip/hip_runtime.h>

typedef unsigned short u16;
typedef unsigned int u32;
typedef long long ll;
typedef __attribute__((ext_vector_type(8))) short bf16x8;
typedef __attribute__((ext_vector_type(8))) unsigned short u16x8;
typedef __attribute__((ext_vector_type(4))) float f32x4;

__device__ __forceinline__ u16 f2bf(float f) {
  u32 x = __float_as_uint(f);
  x += 0x7fffu + ((x >> 16) & 1u);
  return (u16)(x >> 16);
}
__device__ __forceinline__ float bf2f(u16 u) {
  return __uint_as_float(((u32)u) << 16);
}

__device__ __forceinline__ int read_pad(const int* pw, int z) {
  int odd = pw[1] | pw[3] | pw[5] | pw[7] | pw[9] | pw[11] | pw[13] | pw[15];
  return (odd == 0) ? pw[2 * z] : pw[z];
}

// ===========================================================================
// 256x256 GEMM (R5 structure — best measured, 790 TF at K=1024; 93% of the
// verified plain-HIP ceiling m248=848 TF at this K).  C = A * B^T, bf16 in,
// BK=64, 8 waves (2M x 4N), per-wave 128x64 out.  LDS 128 KiB, 2-deep dbuf.
// Per k-slice (32-wide): phase A {read bv+av(mh0) | stage A-unit | bar |
// 16 MFMA | bar}, phase B {read av(mh1), bv cached | stage B-unit | bar |
// 16 MFMA | vmcnt(4) | bar}.  Compiler emits fine-grained lgkmcnt so LDS
// streaming overlaps the MFMA cluster.
// EPI: 0 = scale+mask -> bf16 scores; 1 = plain bf16; 2 = fp32 + bias.
// ===========================================================================
__device__ __forceinline__ void stage_unit(const u16* gsrc, int gld, u16* dst,
                                           int ks, int wid, int lane) {
  const int rsub = lane >> 2;  // row within 16-row chunk
  const int gk = ks * 32 + (((lane & 3) ^ ((lane >> 3) & 3)) * 8);
#pragma unroll
  for (int q = 0; q < 2; ++q) {
    const int r0 = (q * 8 + wid) * 16;
    __builtin_amdgcn_global_load_lds(
        (const __attribute__((address_space(1))) void*)(gsrc + (ll)(r0 + rsub) * gld + gk),
        (__attribute__((address_space(3))) void*)(dst + r0 * 32),
        16, 0, 0);
  }
}

template<int EPI>
__global__ __launch_bounds__(512, 2) void gemm8(
    const u16* __restrict__ A, const u16* __restrict__ B, void* __restrict__ C,
    int Kdim, int lda, int ldb, int ldc, ll sA, ll sB, ll sC,
    const int* __restrict__ pad, const float* __restrict__ bias,
    int NX, int NXY, int nwg) {
  __shared__ __align__(16) u16 ldsA[2][2 * 8192];  // [dbuf][ks*8192 + r*32 + s*8]
  __shared__ __align__(16) u16 ldsB[2][2 * 8192];

  // bijective XCD swizzle (m204) + decode
  const int orig = blockIdx.x;
  const int q8 = nwg >> 3, r8 = nwg & 7;
  const int xcd = orig & 7, inner = orig >> 3;
  const int wg = (xcd < r8 ? xcd * (q8 + 1) : r8 * (q8 + 1) + (xcd - r8) * q8) + inner;
  const int z = wg / NXY;
  const int rem = wg - z * NXY;
  const int by = rem / NX;
  const int bx = rem - by * NX;

  const int tid = threadIdx.x;
  const int wid = tid >> 6, lane = tid & 63;
  const int lr = lane & 15, lg = lane >> 4;
  const int wr = wid >> 2;          // wave m-block (0/1)
  const int wn64 = (wid & 3) * 64;  // wave n-block
  const int bm = by * 256, bn = bx * 256;
  const u16* Ab = A + (ll)z * sA + (ll)bm * lda;
  const u16* Bb = B + (ll)z * sB + (ll)bn * ldb;

  // per-lane ds_read offset: row = base + lr, slot = lg ^ ((lr>>1)&3)
  const int aoff = lr * 32 + ((lg ^ ((lr >> 1) & 3)) * 8);

  f32x4 acc[8][4];
#pragma unroll
  for (int i = 0; i < 8; ++i)
#pragma unroll
    for (int j = 0; j < 4; ++j) acc[i][j] = (f32x4)0.0f;

  // ---- prologue: stage all 4 units of tile 0 into buf 0 -------------------
#pragma unroll
  for (int p = 0; p < 4; ++p) {
    const int ks = p >> 1;
    if (p & 1) stage_unit(Bb, ldb, &ldsB[0][ks * 8192], ks, wid, lane);
    else       stage_unit(Ab, lda, &ldsA[0][ks * 8192], ks, wid, lane);
  }
  asm volatile("s_waitcnt vmcnt(4)" ::: "memory");  // ks0 units landed
  __builtin_amdgcn_s_barrier();

  // ---- main loop ----------------------------------------------------------
  const int NT = Kdim >> 6;
  for (int t = 0; t < NT; ++t) {
    const int c = t & 1;
    u16* A_cur = &ldsA[c][0];
    u16* B_cur = &ldsB[c][0];
    u16* A_nxt = &ldsA[c ^ 1][0];
    u16* B_nxt = &ldsB[c ^ 1][0];
    const u16* Agn = Ab + (t + 1) * 64;
    const u16* Bgn = Bb + (t + 1) * 64;
    const bool stage = (t + 1 < NT);
    const bool last = (t + 1 == NT);
#pragma unroll
    for (int ks = 0; ks < 2; ++ks) {
      bf16x8 av[4], bv[4];
      // ---- phase A (mh=0): bv + av reads, stage A-unit of next tile -------
#pragma unroll
      for (int i = 0; i < 4; ++i) {
        bv[i] = *(const bf16x8*)(B_cur + ks * 8192 + (wn64 + i * 16) * 32 + aoff);
        av[i] = *(const bf16x8*)(A_cur + ks * 8192 + (wr * 128 + i * 16) * 32 + aoff);
      }
      if (stage) stage_unit(Agn, lda, A_nxt + ks * 8192, ks, wid, lane);
      __builtin_amdgcn_s_barrier();
      __builtin_amdgcn_s_setprio(1);
#pragma unroll
      for (int i = 0; i < 4; ++i)
#pragma unroll
        for (int j = 0; j < 4; ++j)
          acc[i][j] = __builtin_amdgcn_mfma_f32_16x16x32_bf16(
              av[i], bv[j], acc[i][j], 0, 0, 0);
      __builtin_amdgcn_s_setprio(0);
      __builtin_amdgcn_s_barrier();
      // ---- phase B (mh=1): av reads only (bv cached), stage B-unit --------
#pragma unroll
      for (int i = 0; i < 4; ++i)
        av[i] = *(const bf16x8*)(A_cur + ks * 8192 +
                                 (wr * 128 + (4 + i) * 16) * 32 + aoff);
      if (stage) stage_unit(Bgn, ldb, B_nxt + ks * 8192, ks, wid, lane);
      __builtin_amdgcn_s_barrier();
      __builtin_amdgcn_s_setprio(1);
#pragma unroll
      for (int i = 0; i < 4; ++i)
#pragma unroll
        for (int j = 0; j < 4; ++j)
          acc[4 + i][j] = __builtin_amdgcn_mfma_f32_16x16x32_bf16(
              av[i], bv[j], acc[4 + i][j], 0, 0, 0);
      __builtin_amdgcn_s_setprio(0);
      if (ks == 0) {
        if (last) asm volatile("s_waitcnt vmcnt(0)" ::: "memory");
        else      asm volatile("s_waitcnt vmcnt(4)" ::: "memory");
      } else if (!last) {
        asm volatile("s_waitcnt vmcnt(4)" ::: "memory");
      }
      __builtin_amdgcn_s_barrier();
    }
  }

  // ---- epilogue: C/D layout col = lane&15, row = (lane>>4)*4 + reg --------
  int p = 0;
  if constexpr (EPI == 0) p = read_pad(pad, z);
#pragma unroll
  for (int mf = 0; mf < 8; ++mf) {
    const int rowb = bm + wr * 128 + mf * 16 + 4 * lg;
#pragma unroll
    for (int nf = 0; nf < 4; ++nf) {
      const int col = bn + wn64 + nf * 16 + lr;
#pragma unroll
      for (int rg = 0; rg < 4; ++rg) {
        const int r = rowb + rg;
        if constexpr (EPI == 0) {
          float v = acc[mf][nf][rg] * 0.03125f;  // 1/sqrt(1024)
          if (r >= p && col >= p) v = -1e13f;
          ((u16*)C)[(ll)z * sC + (ll)r * ldc + col] = f2bf(v);
        } else if constexpr (EPI == 1) {
          ((u16*)C)[(ll)z * sC + (ll)r * ldc + col] = f2bf(acc[mf][nf][rg]);
        } else {
          ((float*)C)[(ll)z * sC + (ll)r * ldc + col] = acc[mf][nf][rg] + bias[col];
        }
      }
    }
  }
}

// ===========================================================================
// Prologue kernels
// ===========================================================================
// Merged fp32->bf16 convert for Q and K (one launch, BW-bound, vectorized).
__global__ __launch_bounds__(256) void cvt2_bf16(
    const float* __restrict__ q, const float* __restrict__ k,
    u16* __restrict__ qb, u16* __restrict__ kb, int nv) {
  int b = blockIdx.x;
  const float* s = q;
  u16* d = qb;
  if (b >= nv) { s = k; d = kb; b -= nv; }
  const ll i = ((ll)b * 256 + threadIdx.x) * 8;
  const float4 a = *(const float4*)(s + i);
  const float4 c = *(const float4*)(s + i + 4);
  u16x8 v;
  v[0] = f2bf(a.x); v[1] = f2bf(a.y); v[2] = f2bf(a.z); v[3] = f2bf(a.w);
  v[4] = f2bf(c.x); v[5] = f2bf(c.y); v[6] = f2bf(c.z); v[7] = f2bf(c.w);
  *(u16x8*)(d + i) = v;
}

// Transpose + fp32->bf16: src [R][C] fp32 -> dst [C][R] bf16.
// Vectorized both sides (G13): float4 loads (16 B/lane), u16x8 stores.
__global__ __launch_bounds__(256) void transpose_cvt(
    const float* __restrict__ src, u16* __restrict__ dst, int R, int C,
    ll sS, ll sD) {
  __shared__ u16 t[64][65];
  const int tid = threadIdx.x;
  const int r0 = blockIdx.y * 64, c0 = blockIdx.x * 64;
  const float* s = src + (ll)blockIdx.z * sS;
  u16* d = dst + (ll)blockIdx.z * sD;
#pragma unroll
  for (int it = 0; it < 4; ++it) {
    const int idx = it * 256 + tid;          // 1024 float4 chunks
    const int r = idx >> 4, c4 = (idx & 15) * 4;
    const float4 v = *(const float4*)(s + (ll)(r0 + r) * C + c0 + c4);
    t[r][c4 + 0] = f2bf(v.x);
    t[r][c4 + 1] = f2bf(v.y);
    t[r][c4 + 2] = f2bf(v.z);
    t[r][c4 + 3] = f2bf(v.w);
  }
  __syncthreads();
#pragma unroll
  for (int it = 0; it < 2; ++it) {
    const int idx = it * 256 + tid;          // 512 u16x8 chunks
    const int rr = idx >> 3, cb = (idx & 7) * 8;
    u16x8 v;
#pragma unroll
    for (int e = 0; e < 8; ++e) v[e] = t[cb + e][rr];
    *(u16x8*)(d + (ll)(c0 + rr) * R + r0 + cb) = v;
  }
}

// In-place row softmax; MASKED variant also applies scale + pad mask.
template<bool MASKED>
__global__ __launch_bounds__(256) void softmax_rows(u16* __restrict__ P,
                                                    const int* __restrict__ pad) {
  const int wid = threadIdx.x >> 6, lane = threadIdx.x & 63;
  const ll row = (ll)blockIdx.x * 4 + wid;
  const int z = (int)(row >> 11);
  const int r = (int)(row & 2047);
  int p = 0;
  bool rmask = false;
  if constexpr (MASKED) {
    p = read_pad(pad, z);
    rmask = (r >= p);
  }
  u16* ptr = P + row * 2048;
  float s[32];
#pragma unroll
  for (int i = 0; i < 4; ++i) {
    const u16x8 v = *(const u16x8*)(ptr + i * 512 + lane * 8);
#pragma unroll
    for (int j = 0; j < 8; ++j) {
      float x = bf2f(v[j]);
      if constexpr (MASKED) {
        const int col = i * 512 + lane * 8 + j;
        x *= 0.03125f;
        if (rmask && col >= p) x = -1e13f;
      }
      s[i * 8 + j] = x;
    }
  }
  float m = s[0];
#pragma unroll
  for (int i = 1; i < 32; ++i) m = fmaxf(m, s[i]);
#pragma unroll
  for (int o = 1; o < 64; o <<= 1) m = fmaxf(m, __shfl_xor(m, o));
  float sum = 0.0f;
#pragma unroll
  for (int i = 0; i < 32; ++i) {
    s[i] = __expf(s[i] - m);
    sum += s[i];
  }
#pragma unroll
  for (int o = 1; o < 64; o <<= 1) sum += __shfl_xor(sum, o);
  const float inv = 1.0f / sum;
#pragma unroll
  for (int i = 0; i < 4; ++i) {
    u16x8 v;
#pragma unroll
    for (int j = 0; j < 8; ++j) v[j] = f2bf(s[i * 8 + j] * inv);
    *(u16x8*)(ptr + i * 512 + lane * 8) = v;
  }
}

// 128² reg-staged fp32-input GEMM (fallback tiers): C = A * B^T, bf16 out.
__device__ __forceinline__ void stage_f32(const float* src, ll base, int ld,
                                          u16* lds, int tid) {
#pragma unroll
  for (int p = 0; p < 4; ++p) {
    int chunk = p * 256 + tid;
    int r = chunk >> 3, slot = chunk & 7;
    const float* s = src + base + (ll)r * ld + slot * 8;
    const float4 a = *(const float4*)s;
    const float4 b = *(const float4*)(s + 4);
    u16x8 v;
    v[0] = f2bf(a.x); v[1] = f2bf(a.y); v[2] = f2bf(a.z); v[3] = f2bf(a.w);
    v[4] = f2bf(b.x); v[5] = f2bf(b.y); v[6] = f2bf(b.z); v[7] = f2bf(b.w);
    *(u16x8*)(lds + r * 64 + (slot ^ (r & 7)) * 8) = v;
  }
}

__global__ __launch_bounds__(256) void gemm_f32in(
    const float* __restrict__ A, const float* __restrict__ B,
    u16* __restrict__ C, int Kdim, int lda, int ldb, int ldc,
    ll sA, ll sB, ll sC) {
  __shared__ __align__(16) u16 As[128 * 64];
  __shared__ __align__(16) u16 Bs[128 * 64];
  const int tid = threadIdx.x;
  const int z = blockIdx.z;
  const int bm = blockIdx.y * 128, bn = blockIdx.x * 128;
  const ll abase = (ll)z * sA + (ll)bm * lda;
  const ll bbase = (ll)z * sB + (ll)bn * ldb;
  const int wid = tid >> 6, lane = tid & 63;
  const int wm = (wid >> 1) * 64, wn = (wid & 1) * 64;
  const int lr = lane & 15, lg = lane >> 4;

  f32x4 acc[4][4];
#pragma unroll
  for (int i = 0; i < 4; ++i)
#pragma unroll
    for (int j = 0; j < 4; ++j) acc[i][j] = (f32x4)0.0f;

  for (int k0 = 0; k0 < Kdim; k0 += 64) {
    __syncthreads();
    stage_f32(A, abase + k0, lda, As, tid);
    stage_f32(B, bbase + k0, ldb, Bs, tid);
    __syncthreads();
#pragma unroll
    for (int kk = 0; kk < 2; ++kk) {
      bf16x8 av[4], bv[4];
#pragma unroll
      for (int i = 0; i < 4; ++i) {
        const int ra = wm + i * 16 + lr;
        av[i] = *(const bf16x8*)(As + ra * 64 + (((kk * 4 + lg) ^ (ra & 7)) * 8));
        const int rb = wn + i * 16 + lr;
        bv[i] = *(const bf16x8*)(Bs + rb * 64 + (((kk * 4 + lg) ^ (rb & 7)) * 8));
      }
#pragma unroll
      for (int i = 0; i < 4; ++i)
#pragma unroll
        for (int j = 0; j < 4; ++j)
          acc[i][j] = __builtin_amdgcn_mfma_f32_16x16x32_bf16(av[i], bv[j],
                                                              acc[i][j], 0, 0, 0);
    }
  }
#pragma unroll
  for (int i = 0; i < 4; ++i) {
    const int rowb = bm + wm + i * 16 + 4 * lg;
#pragma unroll
    for (int j = 0; j < 4; ++j) {
      const int col = bn + wn + j * 16 + lr;
#pragma unroll
      for (int rg = 0; rg < 4; ++rg)
        C[(ll)z * sC + (ll)(rowb + rg) * ldc + col] = f2bf(acc[i][j][rg]);
    }
  }
}

// ===========================================================================
extern "C" void kernel_launch(void* const* d_in, const int* in_sizes, int n_in,
                              void* d_out, int out_size, void* d_ws,
                              size_t ws_size, hipStream_t stream) {
  const float* Q = (const float*)d_in[0];
  const float* Km = (const float*)d_in[1];
  const float* V = (const float*)d_in[2];
  const int* pad = (const int*)d_in[3];
  const float* W = (const float*)d_in[4];
  const float* bias = (const float*)d_in[5];
  float* out = (float*)d_out;

  const int B = 16, S = 2048, D = 1024, E = 1024;
  const ll SS = (ll)S * S, SD = (ll)S * D;

  u16* P = (u16*)d_out;   // 128 MB bf16 scores; final GEMM overwrites
  char* ws = (char*)d_ws;

  const size_t MB64 = (size_t)B * S * D * 2;  // 64 MB
  const size_t szWt = (size_t)D * E * 2;      // 2 MB

  if (ws_size >= 3 * MB64 + szWt) {
    // Tier A: all-bf16, all GEMMs on the 2-barrier/tile 256² kernel (R5).
    u16* Qb = (u16*)ws;
    u16* Kb = (u16*)(ws + MB64);
    u16* Vt = (u16*)(ws + 2 * MB64);
    u16* Wt = (u16*)(ws + 3 * MB64);
    u16* X = Qb;  // aliases Qb (dead after QK)

    const int nv = (int)(((ll)B * S * D) / (8 * 256));  // 16384
    cvt2_bf16<<<dim3(2 * nv), 256, 0, stream>>>(Q, Km, Qb, Kb, nv);
    transpose_cvt<<<dim3(D / 64, S / 64, B), 256, 0, stream>>>(V, Vt, S, D, SD, SD);
    transpose_cvt<<<dim3(E / 64, D / 64, 1), 256, 0, stream>>>(W, Wt, D, E, 0, 0);

    // QK (scale+mask fused): M=N=2048, K=1024, 16 batches -> nwg = 1024
    gemm8<0><<<dim3(1024), 512, 0, stream>>>(
        Qb, Kb, P, D, D, D, S, SD, SD, SS, pad, nullptr, 8, 64, 1024);
    softmax_rows<false><<<dim3(B * S / 4), 256, 0, stream>>>(P, pad);
    // PV: M=2048, N=1024, K=2048 -> nwg = 512
    gemm8<1><<<dim3(512), 512, 0, stream>>>(
        P, Vt, X, S, S, S, D, SS, SD, SD, nullptr, nullptr, 4, 32, 512);
    // out: M=32768, N=1024, K=1024 -> nwg = 512
    gemm8<2><<<dim3(512), 512, 0, stream>>>(
        X, Wt, out, D, D, D, E, 0, 0, 0, nullptr, bias, 4, 512, 512);
  } else if (ws_size >= 2 * MB64 + szWt) {
    // Tier B: fp32-input 128² QK + masked softmax; fast PV/out.
    u16* Vt = (u16*)ws;
    u16* Wt = (u16*)(ws + MB64);
    u16* X = (u16*)(ws + MB64 + szWt);

    transpose_cvt<<<dim3(D / 64, S / 64, B), 256, 0, stream>>>(V, Vt, S, D, SD, SD);
    transpose_cvt<<<dim3(E / 64, D / 64, 1), 256, 0, stream>>>(W, Wt, D, E, 0, 0);
    gemm_f32in<<<dim3(S / 128, S / 128, B), 256, 0, stream>>>(
        Q, Km, P, D, D, D, S, SD, SD, SS);
    softmax_rows<true><<<dim3(B * S / 4), 256, 0, stream>>>(P, pad);
    gemm8<1><<<dim3(512), 512, 0, stream>>>(
        P, Vt, X, S, S, S, D, SS, SD, SD, nullptr, nullptr, 4, 32, 512);
    gemm8<2><<<dim3(512), 512, 0, stream>>>(
        X, Wt, out, D, D, D, E, 0, 0, 0, nullptr, bias, 4, 512, 512);
  } else {
    // Tier C: per-batch V transpose (needs >= 70 MB).
    u16* Wt = (u16*)ws;
    u16* Vtb = (u16*)(ws + szWt);
    u16* X = (u16*)(ws + szWt + (size_t)D * S * 2);

    transpose_cvt<<<dim3(E / 64, D / 64, 1), 256, 0, stream>>>(W, Wt, D, E, 0, 0);
    gemm_f32in<<<dim3(S / 128, S / 128, B), 256, 0, stream>>>(
        Q, Km, P, D, D, D, S, SD, SD, SS);
    softmax_rows<true><<<dim3(B * S / 4), 256, 0, stream>>>(P, pad);
    for (int b = 0; b < B; ++b) {
      transpose_cvt<<<dim3(D / 64, S / 64, 1), 256, 0, stream>>>(
          V + (ll)b * SD, Vtb, S, D, 0, 0);
      gemm8<1><<<dim3(32), 512, 0, stream>>>(
          P + (ll)b * SS, Vtb, X + (ll)b * SD, S, S, S, D, 0, 0, 0, nullptr,
          nullptr, 4, 32, 32);
    }
    gemm8<2><<<dim3(512), 512, 0, stream>>>(
        X, Wt, out, D, D, D, E, 0, 0, 0, nullptr, bias, 4, 512, 512);
  }
}